// Round 1
// baseline (11015.500 us; speedup 1.0000x reference)
//
#include <hip/hip_runtime.h>
#include <math.h>

typedef unsigned short u16;
typedef unsigned int   u32;

#define LN_EPS 1e-5f
#define RS_QK  0.17677669529663687f   // 1/sqrt(32)

__device__ __forceinline__ void unpack8(const uint4 w, float* f) {
  f[0]=__uint_as_float(w.x<<16); f[1]=__uint_as_float(w.x&0xffff0000u);
  f[2]=__uint_as_float(w.y<<16); f[3]=__uint_as_float(w.y&0xffff0000u);
  f[4]=__uint_as_float(w.z<<16); f[5]=__uint_as_float(w.z&0xffff0000u);
  f[6]=__uint_as_float(w.w<<16); f[7]=__uint_as_float(w.w&0xffff0000u);
}

#define DOT8(acc, a0, a1, wf) \
  acc += a0.x*wf[0] + a0.y*wf[1] + a0.z*wf[2] + a0.w*wf[3] \
       + a1.x*wf[4] + a1.y*wf[5] + a1.z*wf[6] + a1.w*wf[7]

__device__ __forceinline__ u16 f2bf(float x){
  u32 u = __float_as_uint(x);
  u32 r = (u + 0x7fffu + ((u>>16)&1u)) >> 16;   // RNE
  return (u16)r;
}

// ---------- prep: bf16 chunk-major weights: W_cm[cc][col][k], k = inner-8 of contraction dim ----------
__global__ void prep_weights(const float* __restrict__ Wem, const float* __restrict__ Wea,
                             const float* __restrict__ Weo, const float* __restrict__ WE1,
                             const float* __restrict__ WE2,
                             u16* __restrict__ wem_cm, u16* __restrict__ wea_cm,
                             u16* __restrict__ weo_cm, u16* __restrict__ we1_cm,
                             u16* __restrict__ we2_cm)
{
  int g = blockIdx.x*256 + threadIdx.x;
  if (g < 16384) {                    // Wem (64x256): [cc<8][d<256][k<8]
    int cc=g>>11, dd=(g>>3)&255, k=g&7;
    wem_cm[g] = f2bf(Wem[(cc*8+k)*256 + dd]);
  } else if (g < 32768) {             // Wea
    int i=g-16384; int cc=i>>11, dd=(i>>3)&255, k=i&7;
    wea_cm[i] = f2bf(Wea[(cc*8+k)*256 + dd]);
  } else if (g < 49152) {             // Weo (256x64): [cc<32][e<64][k<8]
    int i=g-32768; int cc=i>>9, e=(i>>3)&63, k=i&7;
    weo_cm[i] = f2bf(Weo[(cc*8+k)*64 + e]);
  } else if (g < 57344) {             // WE1 (64x128): [cc<8][h<128][k<8]
    int i=g-49152; int cc=i>>10, h=(i>>3)&127, k=i&7;
    we1_cm[i] = f2bf(WE1[(cc*8+k)*128 + h]);
  } else if (g < 65536) {             // WE2 (128x64): [cc<16][e<64][k<8]
    int i=g-57344; int cc=i>>9, e=(i>>3)&63, k=i&7;
    we2_cm[i] = f2bf(WE2[(cc*8+k)*64 + e]);
  }
}

// ---------- QKV: Q/K/V = (X@W + b) * mask, 8 rows per block ----------
__launch_bounds__(256)
__global__ void qkv_kernel(const float* __restrict__ X, const int* __restrict__ mask,
  const float* __restrict__ Wq, const float* __restrict__ bq,
  const float* __restrict__ Wk, const float* __restrict__ bk,
  const float* __restrict__ Wv, const float* __restrict__ bv,
  float* __restrict__ Q, float* __restrict__ K, float* __restrict__ V)
{
  const int t = threadIdx.x, d = t;
  const int r0 = blockIdx.x * 8;
  __shared__ float s_x[8][256];
  __shared__ float s_m[8];
#pragma unroll
  for (int rr=0;rr<8;++rr) s_x[rr][d] = X[(size_t)(r0+rr)*256 + d];
  if (t<8) s_m[t] = (mask[r0+t]!=0)?1.f:0.f;
  __syncthreads();
  float qa[8]={0,0,0,0,0,0,0,0}, ka[8]={0,0,0,0,0,0,0,0}, va[8]={0,0,0,0,0,0,0,0};
  for (int c=0;c<256;++c){
    const float wq = Wq[c*256+d], wk = Wk[c*256+d], wv = Wv[c*256+d];
#pragma unroll
    for (int rr=0;rr<8;++rr){
      const float xv = s_x[rr][c];
      qa[rr]+=xv*wq; ka[rr]+=xv*wk; va[rr]+=xv*wv;
    }
  }
  const float bqd=bq[d], bkd=bk[d], bvd=bv[d];
#pragma unroll
  for (int rr=0;rr<8;++rr){
    const float mf = s_m[rr];
    const size_t o = (size_t)(r0+rr)*256 + d;
    Q[o]=(qa[rr]+bqd)*mf; K[o]=(ka[rr]+bkd)*mf; V[o]=(va[rr]+bvd)*mf;
  }
}

// ---------- heavy: per (b,i): E1/E2 -> Y -> online softmax + V-acc -> newE -> LN/FFN/LN -> Eout ----------
__launch_bounds__(256, 3)
__global__ void heavy_kernel(const float* __restrict__ E, const int* __restrict__ mask,
  const float* __restrict__ Qg, const float* __restrict__ Kg, const float* __restrict__ Vg,
  const float* __restrict__ bem, const float* __restrict__ bea, const float* __restrict__ beo,
  const float* __restrict__ bE1, const float* __restrict__ bE2,
  const float* __restrict__ gE1, const float* __restrict__ bnE1,
  const float* __restrict__ gE2, const float* __restrict__ bnE2,
  const u16* __restrict__ wem_cm, const u16* __restrict__ wea_cm, const u16* __restrict__ weo_cm,
  const u16* __restrict__ we1_cm, const u16* __restrict__ we2_cm,
  float* __restrict__ WV, float* __restrict__ Eout)
{
  const int t  = threadIdx.x;
  const int bi = blockIdx.x;           // b*256 + i
  const int b  = bi >> 8;
  const int rb = b << 8;

  __shared__ u16   s_we1[8192];        // 16KB  WE1 chunk-major
  __shared__ u16   s_we2[8192];        // 16KB  WE2 chunk-major
  __shared__ float s_et[8][64];        // 2KB   E tile (8 j-rows)
  __shared__ float s_y[2048];          // 8KB   Y[8][256]; later overlaid: partials / e1n / hid
  __shared__ float s_ne[8][64];        // 2KB   newE
  __shared__ float s_mask[256];        // 1KB

  {
    const uint4* s1 = (const uint4*)we1_cm; uint4* d1 = (uint4*)s_we1;
    const uint4* s2 = (const uint4*)we2_cm; uint4* d2 = (uint4*)s_we2;
    for (int k=t; k<1024; k+=256){ d1[k]=s1[k]; d2[k]=s2[k]; }
    s_mask[t] = (mask[rb + t] != 0) ? 1.f : 0.f;
  }
  const float mi = (mask[bi] != 0) ? 1.f : 0.f;
  const int d = t;
  const float q_d   = Qg[(size_t)bi*256 + d];
  const float bem_d = bem[d], bea_d = bea[d];

  const int g4 = t>>5, r4 = t&31;      // phase-4 row group / lane
  const float be1_0=bE1[r4], be1_1=bE1[r4+32], be1_2=bE1[r4+64], be1_3=bE1[r4+96];
  const float be2_0=bE2[r4], be2_1=bE2[r4+32];
  const float ga1_0=gE1[r4], ga1_1=gE1[r4+32], bb1_0=bnE1[r4], bb1_1=bnE1[r4+32];
  const float ga2_0=gE2[r4], ga2_1=gE2[r4+32], bb2_0=bnE2[r4], bb2_1=bnE2[r4+32];
  const int e3 = t&63, qq3 = t>>6;     // phase-3 col / quarter
  const float beo_e = beo[e3];

  float sm_m = -3.0e38f, sm_l = 0.f, sm_acc = 0.f;   // per-channel online softmax state

  __syncthreads();

  for (int ch=0; ch<32; ++ch) {
    const int j0 = ch*8;
    {
      const float4* esrc = (const float4*)(E + ((size_t)bi*256 + j0)*64);
      if (t < 128) ((float4*)s_et)[t] = esrc[t];
    }
    __syncthreads();

    // ---- phase 1: E1/E2 = Etile @ Wem/Wea (thread = output channel d, 8 j-rows) ----
    float e1a[8], e2a[8];
#pragma unroll
    for (int jj=0;jj<8;++jj){ e1a[jj]=0.f; e2a[jj]=0.f; }
#pragma unroll
    for (int cc=0; cc<8; ++cc) {
      uint4 w1 = ((const uint4*)wem_cm)[cc*256 + d];
      uint4 w2 = ((const uint4*)wea_cm)[cc*256 + d];
      float f1[8], f2v[8];
      unpack8(w1,f1); unpack8(w2,f2v);
#pragma unroll
      for (int jj=0;jj<8;++jj) {
        const float4* ep = (const float4*)&s_et[jj][cc*8];
        float4 ea = ep[0], eb = ep[1];
        DOT8(e1a[jj], ea, eb, f1);
        DOT8(e2a[jj], ea, eb, f2v);
      }
    }

    // ---- phase 2: Y, online softmax (axis=j, per channel), V accumulation ----
#pragma unroll
    for (int jj=0;jj<8;++jj) {
      const float mj = s_mask[j0+jj];              // uniform across block
      const float pm = mi * mj;
      const float e1 = (e1a[jj] + bem_d) * pm;
      const float e2 = (e2a[jj] + bea_d) * pm;
      const float kv = Kg[(size_t)(rb + j0 + jj)*256 + d];
      float y = q_d * kv * RS_QK;
      y = y * (e1 + 1.f) + e2;
      s_y[jj*256 + d] = y;
      if (mj > 0.f) {
        const float mn = fmaxf(sm_m, y);
        const float sc = __expf(sm_m - mn);
        const float p  = __expf(y - mn);
        const float vv = Vg[(size_t)(rb + j0 + jj)*256 + d];
        sm_l   = sm_l  * sc + p;
        sm_acc = sm_acc* sc + p * vv;
        sm_m   = mn;
      }
    }
    __syncthreads();

    // ---- phase 3a: newE partials (thread = (e, k-quarter), 8 j-rows) ----
    float pacc[8];
#pragma unroll
    for (int jj=0;jj<8;++jj) pacc[jj]=0.f;
#pragma unroll
    for (int c2=0;c2<8;++c2) {
      const int cc = qq3*8 + c2;
      uint4 w = ((const uint4*)weo_cm)[cc*64 + e3];
      float wf[8]; unpack8(w,wf);
#pragma unroll
      for (int jj=0;jj<8;++jj) {
        const float4* yp = (const float4*)&s_y[jj*256 + cc*8];
        float4 ya = yp[0], yb = yp[1];
        DOT8(pacc[jj], ya, yb, wf);
      }
    }
    __syncthreads();
#pragma unroll
    for (int jj=0;jj<8;++jj) s_y[qq3*512 + jj*64 + e3] = pacc[jj];   // overlay partials
    __syncthreads();

    // ---- phase 3b: reduce 4 partials + bias + epair mask ----
#pragma unroll
    for (int h2=0; h2<2; ++h2) {
      const int o = t + 256*h2;
      const int jj = o >> 6, ee = o & 63;          // ee == e3 for both
      float sum = s_y[jj*64+ee] + s_y[512+jj*64+ee] + s_y[1024+jj*64+ee] + s_y[1536+jj*64+ee];
      s_ne[jj][ee] = (sum + beo_e) * (mi * s_mask[j0+jj]);
    }
    __syncthreads();

    // ---- phase 4: E-residual LN -> FFN(64->128->64) -> LN -> Eout ----
    float* s_e1n = s_y;            // [8][64]
    float* s_hid = s_y + 512;      // [8][128]
    float z0 = s_et[g4][r4]    + s_ne[g4][r4];
    float z1 = s_et[g4][r4+32] + s_ne[g4][r4+32];
    float rsum = z0+z1, rsq = z0*z0+z1*z1;
#pragma unroll
    for (int mk=16; mk; mk>>=1){ rsum += __shfl_xor(rsum,mk); rsq += __shfl_xor(rsq,mk); }
    float mean1 = rsum*(1.f/64.f);
    float inv1  = rsqrtf(rsq*(1.f/64.f) - mean1*mean1 + LN_EPS);
    float a0 = (z0-mean1)*inv1*ga1_0 + bb1_0;
    float a1 = (z1-mean1)*inv1*ga1_1 + bb1_1;
    s_e1n[g4*64 + r4]    = a0;
    s_e1n[g4*64 + r4+32] = a1;
    __syncthreads();

    float hb[4]; hb[0]=be1_0; hb[1]=be1_1; hb[2]=be1_2; hb[3]=be1_3;
#pragma unroll
    for (int cc=0; cc<8; ++cc) {
      const float4* ap = (const float4*)&s_e1n[g4*64 + cc*8];
      float4 aa = ap[0], ab = ap[1];
#pragma unroll
      for (int k=0;k<4;++k) {
        uint4 w = ((const uint4*)s_we1)[cc*128 + r4 + 32*k];
        float wf[8]; unpack8(w,wf);
        DOT8(hb[k], aa, ab, wf);
      }
    }
#pragma unroll
    for (int k=0;k<4;++k) s_hid[g4*128 + r4 + 32*k] = fmaxf(hb[k], 0.f);
    __syncthreads();

    float zz0, zz1;
    {
      float acc0 = be2_0, acc1 = be2_1;
#pragma unroll
      for (int cc=0; cc<16; ++cc) {
        const float4* hp = (const float4*)&s_hid[g4*128 + cc*8];
        float4 h0 = hp[0], h1 = hp[1];
        uint4 wA = ((const uint4*)s_we2)[cc*64 + r4];
        float wfA[8]; unpack8(wA,wfA);
        DOT8(acc0, h0, h1, wfA);
        uint4 wB = ((const uint4*)s_we2)[cc*64 + r4 + 32];
        float wfB[8]; unpack8(wB,wfB);
        DOT8(acc1, h0, h1, wfB);
      }
      zz0 = a0 + acc0;
      zz1 = a1 + acc1;
    }
    float rsum2 = zz0+zz1, rsq2 = zz0*zz0+zz1*zz1;
#pragma unroll
    for (int mk=16; mk; mk>>=1){ rsum2 += __shfl_xor(rsum2,mk); rsq2 += __shfl_xor(rsq2,mk); }
    float mean2 = rsum2*(1.f/64.f);
    float inv2  = rsqrtf(rsq2*(1.f/64.f) - mean2*mean2 + LN_EPS);
    size_t ebase = ((size_t)bi*256 + (size_t)(j0+g4))*64;
    Eout[ebase + r4]      = (zz0-mean2)*inv2*ga2_0 + bb2_0;
    Eout[ebase + r4 + 32] = (zz1-mean2)*inv2*ga2_1 + bb2_1;
    // next chunk's first __syncthreads() (after E-tile load) protects the overlays
  }

  const float wv = (sm_l > 0.f) ? (sm_acc / sm_l) : 0.f;
  WV[(size_t)bi*256 + d] = wv;
}

// ---------- X path: newX -> LN -> FFN(256->1024->256) -> LN, 4 rows per block ----------
__launch_bounds__(256)
__global__ void xpath_kernel(const float* __restrict__ X, const int* __restrict__ mask,
  const float* __restrict__ WVg, const float* __restrict__ Wxo, const float* __restrict__ bxo,
  const float* __restrict__ WX1, const float* __restrict__ bX1,
  const float* __restrict__ WX2, const float* __restrict__ bX2,
  const float* __restrict__ gX1, const float* __restrict__ bnX1,
  const float* __restrict__ gX2, const float* __restrict__ bnX2,
  float* __restrict__ Xout)
{
  const int t = threadIdx.x, d = t;
  const int r0 = blockIdx.x * 4;
  __shared__ float s_x[4][256];
  __shared__ float s_wv[4][256];
  __shared__ float s_x1[4][256];
  __shared__ float s_hid[4][1024];
  __shared__ float s_stat[4][2];
  __shared__ float s_m[4];

#pragma unroll
  for (int rr=0;rr<4;++rr){
    s_x[rr][d]  = X[(size_t)(r0+rr)*256 + d];
    s_wv[rr][d] = WVg[(size_t)(r0+rr)*256 + d];
  }
  if (t < 4) s_m[t] = (mask[r0+t] != 0) ? 1.f : 0.f;
  __syncthreads();

  float nx[4] = {0,0,0,0};
  for (int c=0;c<256;++c){
    const float w = Wxo[c*256 + d];
#pragma unroll
    for (int rr=0;rr<4;++rr) nx[rr] += s_wv[rr][c]*w;
  }
  const float bx = bxo[d];
  float z[4];
#pragma unroll
  for (int rr=0;rr<4;++rr) z[rr] = s_x[rr][d] + (nx[rr]+bx)*s_m[rr];

  // LN1
#pragma unroll
  for (int rr=0;rr<4;++rr) s_x1[rr][d] = z[rr];
  __syncthreads();
  {
    const int gg = t>>6, ll = t&63;
    float s=0.f, q=0.f;
#pragma unroll
    for (int k=0;k<4;++k){ float v = s_x1[gg][ll+64*k]; s+=v; q+=v*v; }
#pragma unroll
    for (int mk=32; mk; mk>>=1){ s += __shfl_xor(s,mk); q += __shfl_xor(q,mk); }
    if (ll==0){
      float mean = s*(1.f/256.f);
      s_stat[gg][0] = mean;
      s_stat[gg][1] = rsqrtf(q*(1.f/256.f) - mean*mean + LN_EPS);
    }
  }
  __syncthreads();
  float x1v[4];
  const float g1 = gX1[d], b1 = bnX1[d];
#pragma unroll
  for (int rr=0;rr<4;++rr){
    x1v[rr] = (z[rr]-s_stat[rr][0])*s_stat[rr][1]*g1 + b1;
    s_x1[rr][d] = x1v[rr];
  }
  __syncthreads();

  // FF1
  float ha[4][4];
#pragma unroll
  for (int k=0;k<4;++k){
#pragma unroll
    for (int rr=0;rr<4;++rr) ha[k][rr]=0.f;
  }
  for (int c=0;c<256;++c){
    const float w0 = WX1[(size_t)c*1024 + t];
    const float w1 = WX1[(size_t)c*1024 + t + 256];
    const float w2 = WX1[(size_t)c*1024 + t + 512];
    const float w3 = WX1[(size_t)c*1024 + t + 768];
#pragma unroll
    for (int rr=0;rr<4;++rr){
      const float xv = s_x1[rr][c];
      ha[0][rr] += xv*w0; ha[1][rr] += xv*w1; ha[2][rr] += xv*w2; ha[3][rr] += xv*w3;
    }
  }
#pragma unroll
  for (int k=0;k<4;++k){
    const float bh = bX1[t + 256*k];
#pragma unroll
    for (int rr=0;rr<4;++rr) s_hid[rr][t+256*k] = fmaxf(ha[k][rr]+bh, 0.f);
  }
  __syncthreads();

  // FF2
  float f2a[4] = {0,0,0,0};
#pragma unroll 4
  for (int hh=0; hh<1024; ++hh){
    const float w = WX2[(size_t)hh*256 + d];
#pragma unroll
    for (int rr=0;rr<4;++rr) f2a[rr] += s_hid[rr][hh]*w;
  }
  const float b2 = bX2[d];
  float z2[4];
#pragma unroll
  for (int rr=0;rr<4;++rr) z2[rr] = x1v[rr] + f2a[rr] + b2;

  // LN2
#pragma unroll
  for (int rr=0;rr<4;++rr) s_x1[rr][d] = z2[rr];
  __syncthreads();
  {
    const int gg = t>>6, ll = t&63;
    float s=0.f, q=0.f;
#pragma unroll
    for (int k=0;k<4;++k){ float v = s_x1[gg][ll+64*k]; s+=v; q+=v*v; }
#pragma unroll
    for (int mk=32; mk; mk>>=1){ s += __shfl_xor(s,mk); q += __shfl_xor(q,mk); }
    if (ll==0){
      float mean = s*(1.f/256.f);
      s_stat[gg][0] = mean;
      s_stat[gg][1] = rsqrtf(q*(1.f/256.f) - mean*mean + LN_EPS);
    }
  }
  __syncthreads();
  const float g2 = gX2[d], b2n = bnX2[d];
#pragma unroll
  for (int rr=0;rr<4;++rr)
    Xout[(size_t)(r0+rr)*256 + d] = (z2[rr]-s_stat[rr][0])*s_stat[rr][1]*g2 + b2n;
}

extern "C" void kernel_launch(void* const* d_in, const int* in_sizes, int n_in,
                              void* d_out, int out_size, void* d_ws, size_t ws_size,
                              hipStream_t stream)
{
  const float* X   = (const float*)d_in[0];
  const float* E   = (const float*)d_in[1];
  const int*  mask = (const int*)  d_in[2];
  const float* Wq  = (const float*)d_in[3];
  const float* bq  = (const float*)d_in[4];
  const float* Wk  = (const float*)d_in[5];
  const float* bk  = (const float*)d_in[6];
  const float* Wv  = (const float*)d_in[7];
  const float* bv  = (const float*)d_in[8];
  const float* Wem = (const float*)d_in[9];
  const float* bem = (const float*)d_in[10];
  const float* Wea = (const float*)d_in[11];
  const float* bea = (const float*)d_in[12];
  const float* Wxo = (const float*)d_in[13];
  const float* bxo = (const float*)d_in[14];
  const float* Weo = (const float*)d_in[15];
  const float* beo = (const float*)d_in[16];
  const float* WX1 = (const float*)d_in[17];
  const float* bX1 = (const float*)d_in[18];
  const float* WX2 = (const float*)d_in[19];
  const float* bX2 = (const float*)d_in[20];
  const float* gX1 = (const float*)d_in[21];
  const float* bnX1= (const float*)d_in[22];
  const float* gX2 = (const float*)d_in[23];
  const float* bnX2= (const float*)d_in[24];
  const float* WE1 = (const float*)d_in[25];
  const float* bE1 = (const float*)d_in[26];
  const float* WE2 = (const float*)d_in[27];
  const float* bE2 = (const float*)d_in[28];
  const float* gE1 = (const float*)d_in[29];
  const float* bnE1= (const float*)d_in[30];
  const float* gE2 = (const float*)d_in[31];
  const float* bnE2= (const float*)d_in[32];

  float* out = (float*)d_out;          // Xout [262144] then Eout [16777216]
  float* wsf = (float*)d_ws;
  float* Q   = wsf;                    // [1024][256]
  float* K   = wsf + 262144;
  float* V   = wsf + 524288;
  float* WVp = wsf + 786432;
  u16* wcm    = (u16*)(wsf + 1048576); // 128KB of bf16 packed weights
  u16* wem_cm = wcm;
  u16* wea_cm = wcm + 16384;
  u16* weo_cm = wcm + 32768;
  u16* we1_cm = wcm + 49152;
  u16* we2_cm = wcm + 57344;

  prep_weights<<<256,256,0,stream>>>(Wem,Wea,Weo,WE1,WE2, wem_cm,wea_cm,weo_cm,we1_cm,we2_cm);
  qkv_kernel<<<128,256,0,stream>>>(X, mask, Wq,bq,Wk,bk,Wv,bv, Q,K,V);
  heavy_kernel<<<1024,256,0,stream>>>(E, mask, Q,K,V, bem,bea,beo,bE1,bE2,
                                      gE1,bnE1,gE2,bnE2,
                                      wem_cm,wea_cm,weo_cm,we1_cm,we2_cm,
                                      WVp, out + 262144);
  xpath_kernel<<<256,256,0,stream>>>(X, mask, WVp, Wxo,bxo,WX1,bX1,WX2,bX2,
                                     gX1,bnX1,gX2,bnX2, out);
}